// Round 2
// baseline (1987.244 us; speedup 1.0000x reference)
//
#include <hip/hip_runtime.h>
#include <math.h>

#define VOCAB 100000
#define DIM   128
#define BATCH 2048
#define HIST  50
#define TOPK  10
#define NCAND 32

// ---------------------------------------------------------------------------
// Kernel A: context encoder in fp64, rounded to fp32 for the big GEMM.
// ---------------------------------------------------------------------------
__global__ __launch_bounds__(128) void ctx_kernel(
    const int* __restrict__ ids, const float* __restrict__ cet,
    const float* __restrict__ W, const float* __restrict__ bias,
    float* __restrict__ ctx32)
{
    int b = blockIdx.x;
    int d = threadIdx.x;
    __shared__ int sids[HIST];
    __shared__ double pooled[DIM];
    if (d < HIST) sids[d] = ids[b * HIST + d];
    __syncthreads();
    double s = 0.0;
    for (int h = 0; h < HIST; ++h)
        s += (double)cet[(long)sids[h] * DIM + d];
    pooled[d] = s / (double)HIST;
    __syncthreads();
    double acc = (double)bias[d];
    #pragma unroll 4
    for (int k = 0; k < DIM; ++k)
        acc += pooled[k] * (double)W[k * DIM + d];
    ctx32[b * DIM + d] = (float)acc;
}

// ---------------------------------------------------------------------------
// Kernel B: fp32 GEMM  logits[2048,100000] = ctx[2048,128] @ L^T
// 128x128 tile per 256-thread block, 8x8 micro-tile, K staged in 32-chunks.
// (unchanged from round 1 — output 0 passed)
// ---------------------------------------------------------------------------
#define BM 128
#define BN 128
#define KB 32
#define LDT 132   // padded LDS leading stride (words)

__global__ __launch_bounds__(256) void gemm_kernel(
    const float* __restrict__ ctx, const float* __restrict__ L,
    float* __restrict__ out)
{
    __shared__ float As[KB][LDT];   // As[k][m]
    __shared__ float Bs[KB][LDT];   // Bs[k][n]

    const int t   = threadIdx.x;
    const int bm0 = blockIdx.y * BM;
    const int bn0 = blockIdx.x * BN;
    const int tx  = t & 15, ty = t >> 4;
    const int m0  = ty * 8, n0 = tx * 8;

    const int sr = t >> 3;          // 0..31
    const int sc = (t & 7) * 4;     // 0..28

    float acc[8][8];
    #pragma unroll
    for (int i = 0; i < 8; ++i)
        #pragma unroll
        for (int j = 0; j < 8; ++j) acc[i][j] = 0.f;

    for (int k0 = 0; k0 < DIM; k0 += KB) {
        float4 av[4], bv[4];
        #pragma unroll
        for (int i = 0; i < 4; ++i) {
            av[i] = *(const float4*)&ctx[(bm0 + sr + 32 * i) * DIM + k0 + sc];
            int v = bn0 + sr + 32 * i;
            if (v < VOCAB) bv[i] = *(const float4*)&L[(long)v * DIM + k0 + sc];
            else           bv[i] = make_float4(0.f, 0.f, 0.f, 0.f);
        }
        __syncthreads();
        #pragma unroll
        for (int i = 0; i < 4; ++i) {
            int m = sr + 32 * i;
            As[sc + 0][m] = av[i].x; As[sc + 1][m] = av[i].y;
            As[sc + 2][m] = av[i].z; As[sc + 3][m] = av[i].w;
            Bs[sc + 0][m] = bv[i].x; Bs[sc + 1][m] = bv[i].y;
            Bs[sc + 2][m] = bv[i].z; Bs[sc + 3][m] = bv[i].w;
        }
        __syncthreads();
        #pragma unroll 4
        for (int k = 0; k < KB; ++k) {
            float4 a0 = *(const float4*)&As[k][m0];
            float4 a1 = *(const float4*)&As[k][m0 + 4];
            float4 b0 = *(const float4*)&Bs[k][n0];
            float4 b1 = *(const float4*)&Bs[k][n0 + 4];
            float a[8] = {a0.x, a0.y, a0.z, a0.w, a1.x, a1.y, a1.z, a1.w};
            float bb[8] = {b0.x, b0.y, b0.z, b0.w, b1.x, b1.y, b1.z, b1.w};
            #pragma unroll
            for (int mi = 0; mi < 8; ++mi)
                #pragma unroll
                for (int ni = 0; ni < 8; ++ni)
                    acc[mi][ni] += a[mi] * bb[ni];
        }
    }

    if (bn0 + n0 < VOCAB) {   // VOCAB % 8 == 0
        #pragma unroll
        for (int mi = 0; mi < 8; ++mi) {
            long row = bm0 + m0 + mi;
            float4 o0 = make_float4(acc[mi][0], acc[mi][1], acc[mi][2], acc[mi][3]);
            float4 o1 = make_float4(acc[mi][4], acc[mi][5], acc[mi][6], acc[mi][7]);
            *(float4*)&out[row * VOCAB + bn0 + n0]     = o0;
            *(float4*)&out[row * VOCAB + bn0 + n0 + 4] = o1;
        }
    }
}

// ---------------------------------------------------------------------------
// Kernel C: per-row top-32 candidates from fp32 logits. (unchanged)
// ---------------------------------------------------------------------------
__global__ __launch_bounds__(256) void cand_kernel(
    const float* __restrict__ logits, int* __restrict__ cand)
{
    const int b = blockIdx.x, t = threadIdx.x;
    const float* row = logits + (long)b * VOCAB;

    float bs[8]; int bid[8];
    #pragma unroll
    for (int j = 0; j < 8; ++j) { bs[j] = -INFINITY; bid[j] = 0x7fffffff; }

    for (int v = t; v < VOCAB; v += 256) {
        float s = row[v];
        if (s > bs[7]) {
            int p = 7;
            while (p > 0 && s > bs[p - 1]) { bs[p] = bs[p - 1]; bid[p] = bid[p - 1]; --p; }
            bs[p] = s; bid[p] = v;
        }
    }

    __shared__ float ls[2048];
    __shared__ int   lid[2048];
    __shared__ float rs[4];
    __shared__ int   rid[4], rpos[4];
    #pragma unroll
    for (int j = 0; j < 8; ++j) { ls[t * 8 + j] = bs[j]; lid[t * 8 + j] = bid[j]; }
    __syncthreads();

    const int lane = t & 63, wave = t >> 6;
    for (int r = 0; r < NCAND; ++r) {
        float s = -INFINITY; int id = 0x7fffffff, pos = -1;
        #pragma unroll
        for (int j = 0; j < 8; ++j) {
            int p = t * 8 + j;
            float v = ls[p]; int vi = lid[p];
            if (v > s || (v == s && vi < id)) { s = v; id = vi; pos = p; }
        }
        #pragma unroll
        for (int off = 32; off > 0; off >>= 1) {
            float os = __shfl_down(s, off);
            int   oi = __shfl_down(id, off);
            int   op = __shfl_down(pos, off);
            if (os > s || (os == s && oi < id)) { s = os; id = oi; pos = op; }
        }
        if (lane == 0) { rs[wave] = s; rid[wave] = id; rpos[wave] = pos; }
        __syncthreads();
        if (t == 0) {
            float ws = rs[0]; int wi = rid[0], wp = rpos[0];
            for (int w = 1; w < 4; ++w)
                if (rs[w] > ws || (rs[w] == ws && rid[w] < wi)) { ws = rs[w]; wi = rid[w]; wp = rpos[w]; }
            cand[b * NCAND + r] = wi;
            ls[wp] = -INFINITY;
        }
        __syncthreads();
    }
}

// ---------------------------------------------------------------------------
// Kernel D: fp64 re-rank of candidates. Recomputes ctx in fp64 directly from
// the raw inputs (no ws dependence). Ranking key = fp32-quantized fp64 score,
// ties broken by lower id (mimics np's (fp32 value, index) order).
// ---------------------------------------------------------------------------
__global__ __launch_bounds__(64) void refine_kernel(
    const int* __restrict__ ids, const float* __restrict__ cet,
    const float* __restrict__ W, const float* __restrict__ bias,
    const float* __restrict__ L, const int* __restrict__ cand,
    float* __restrict__ out_ids, float* __restrict__ out_scores)
{
    const int b = blockIdx.x, l = threadIdx.x;   // 64 lanes
    __shared__ int    sids[HIST];
    __shared__ double pooled[DIM];
    if (l < HIST) sids[l] = ids[b * HIST + l];
    __syncthreads();
    #pragma unroll
    for (int d = l; d < DIM; d += 64) {
        double s = 0.0;
        for (int h = 0; h < HIST; ++h)
            s += (double)cet[(long)sids[h] * DIM + d];
        pooled[d] = s / (double)HIST;
    }
    __syncthreads();
    double c0 = (double)bias[l], c1 = (double)bias[l + 64];
    for (int k = 0; k < DIM; ++k) {
        double p = pooled[k];
        c0 += p * (double)W[k * DIM + l];
        c1 += p * (double)W[k * DIM + l + 64];
    }

    __shared__ double ss[NCAND];
    __shared__ int    sidv[NCAND];
    for (int c = 0; c < NCAND; ++c) {
        int id = cand[b * NCAND + c];
        double p = c0 * (double)L[(long)id * DIM + l]
                 + c1 * (double)L[(long)id * DIM + 64 + l];
        #pragma unroll
        for (int off = 32; off > 0; off >>= 1) p += __shfl_down(p, off);
        if (l == 0) { ss[c] = p; sidv[c] = id; }
    }
    __syncthreads();
    if (l == 0) {
        bool used[NCAND];
        for (int c = 0; c < NCAND; ++c) used[c] = false;
        for (int i = 0; i < TOPK; ++i) {
            int bi = -1; float bk = -INFINITY; int bidv = 0x7fffffff;
            for (int c = 0; c < NCAND; ++c) {
                if (used[c]) continue;
                float k32 = (float)ss[c];                     // np-like fp32 key
                if (bi < 0 || k32 > bk || (k32 == bk && sidv[c] < bidv)) {
                    bk = k32; bi = c; bidv = sidv[c];
                }
            }
            used[bi] = true;
            out_ids[b * TOPK + i]    = (float)bidv;
            out_scores[b * TOPK + i] = bk;
        }
    }
}

// ---------------------------------------------------------------------------
extern "C" void kernel_launch(void* const* d_in, const int* in_sizes, int n_in,
                              void* d_out, int out_size, void* d_ws, size_t ws_size,
                              hipStream_t stream)
{
    const int*   ids  = (const int*)d_in[0];
    const float* cet  = (const float*)d_in[1];
    const float* let  = (const float*)d_in[2];
    const float* W    = (const float*)d_in[3];
    const float* bias = (const float*)d_in[4];

    float* out        = (float*)d_out;
    float* logits     = out;                                   // [2048,100000]
    float* out_ids    = out + (long)BATCH * VOCAB;             // [2048,10]
    float* out_scores = out_ids + BATCH * TOPK;                // [2048,10]

    // ws footprint: 1 MB + 256 KB = 1.25 MB total
    char* ws = (char*)d_ws;
    float* ctx32 = (float*)ws;                                 // [2048,128] fp32
    int*   cand  = (int*)(ws + (size_t)BATCH * DIM * 4);       // [2048,32]

    ctx_kernel<<<BATCH, 128, 0, stream>>>(ids, cet, W, bias, ctx32);

    dim3 grid((VOCAB + BN - 1) / BN, BATCH / BM);   // 782 x 16
    gemm_kernel<<<grid, 256, 0, stream>>>(ctx32, let, logits);

    cand_kernel<<<BATCH, 256, 0, stream>>>(logits, cand);

    refine_kernel<<<BATCH, 64, 0, stream>>>(ids, cet, W, bias, let, cand,
                                            out_ids, out_scores);
}